// Round 11
// baseline (619.185 us; speedup 1.0000x reference)
//
#include <hip/hip_runtime.h>
#include <math.h>

#define HDIM 256
#define NMOL 4096
#define NPROT 4096
#define NEDGE 65536
#define NG 32

typedef _Float16 f16x8 __attribute__((ext_vector_type(8)));
typedef _Float16 f16x4 __attribute__((ext_vector_type(4)));
typedef __attribute__((ext_vector_type(4))) float f32x4;

__device__ __forceinline__ void splitf(float x, _Float16& h, _Float16& l) {
  h = (_Float16)x;
  l = (_Float16)(x - (float)h);
}

struct __align__(16) EdgeRec { int src; float a0; float a1; int pad; };

// ---------------------------------------------------------------------------
// Transpose + convert 14 H x H fp32 weights into split f16 planes Wt[n][k].
struct PtrPack { const float* p[14]; };

__global__ __launch_bounds__(256) void k_prep_wt(PtrPack pk, _Float16* __restrict__ dh,
                                                 _Float16* __restrict__ dl) {
  __shared__ float Ts[64][68];
  const int m = blockIdx.z;
  const int n0 = blockIdx.y * 64, k0 = blockIdx.x * 64;
  const float* W = pk.p[m];
  const int t = threadIdx.x;
#pragma unroll
  for (int rep = 0; rep < 16; ++rep) {
    int k = rep * 4 + (t >> 6);
    int n = t & 63;
    Ts[n][k] = W[(size_t)(k0 + k) * 256 + n0 + n];
  }
  __syncthreads();
#pragma unroll
  for (int rep = 0; rep < 2; ++rep) {
    int idx = t + rep * 256;
    int nr = idx >> 3, koff = (idx & 7) * 8;
    f16x8 vh, vl;
#pragma unroll
    for (int i = 0; i < 8; ++i) {
      _Float16 h, l;
      splitf(Ts[nr][koff + i], h, l);
      vh[i] = h; vl[i] = l;
    }
    size_t off = (size_t)m * 65536 + (size_t)(n0 + nr) * 256 + k0 + koff;
    *(f16x8*)&dh[off] = vh;
    *(f16x8*)&dl[off] = vl;
  }
}

// ---------------------------------------------------------------------------
// node embedding -> split planes, both graphs per dispatch
struct EmbJob {
  const float* x; const float* w; const float* b;
  _Float16* oh; _Float16* ol; int K;
};

__global__ __launch_bounds__(256) void k_node_embed2(EmbJob j0, EmbJob j1) {
  const EmbJob& j = blockIdx.y ? j1 : j0;
  const int i = blockIdx.x;
  const int c = threadIdx.x;
  float acc = j.b[c];
  for (int k = 0; k < j.K; ++k) acc += j.x[i * j.K + k] * j.w[k * HDIM + c];
  _Float16 h, l;
  splitf(acc, h, l);
  j.oh[(size_t)i * HDIM + c] = h;
  j.ol[(size_t)i * HDIM + c] = l;
}

// ---------------------------------------------------------------------------
// Whole CSR build in ONE dispatch: 2 blocks (one per graph) x 1024 threads.
// LDS counters -> shfl scan -> scatter packed EdgeRecs.
__global__ __launch_bounds__(1024) void k_csr_all(
    const int* __restrict__ ei0, const int* __restrict__ ei1,
    const float* __restrict__ ea0, const float* __restrict__ ea1,
    int* __restrict__ off0, int* __restrict__ off1,
    EdgeRec* __restrict__ er0, EdgeRec* __restrict__ er1) {
  __shared__ int lcnt[4096];
  __shared__ int wbase[16];
  const int dir = blockIdx.x;
  const int* ei = dir ? ei1 : ei0;
  const float* ea = dir ? ea1 : ea0;
  int* off = dir ? off1 : off0;
  EdgeRec* er = dir ? er1 : er0;
  const int t = threadIdx.x;
  const int lane = t & 63, wv = t >> 6;

#pragma unroll
  for (int i = 0; i < 4; ++i) lcnt[t + i * 1024] = 0;
  __syncthreads();
  for (int e = t; e < NEDGE; e += 1024) atomicAdd(&lcnt[ei[NEDGE + e]], 1);
  __syncthreads();

  int loc[4], s = 0;
#pragma unroll
  for (int i = 0; i < 4; ++i) { loc[i] = lcnt[t * 4 + i]; s += loc[i]; }
  // inclusive scan of s within the wave
  int pre = s;
#pragma unroll
  for (int o = 1; o < 64; o <<= 1) {
    int v = __shfl_up(pre, o, 64);
    if (lane >= o) pre += v;
  }
  if (lane == 63) wbase[wv] = pre;
  __syncthreads();
  if (t == 0) {
    int a = 0;
    for (int i = 0; i < 16; ++i) { int v = wbase[i]; wbase[i] = a; a += v; }
  }
  __syncthreads();
  int a = wbase[wv] + pre - s;  // exclusive prefix for this thread's 4 nodes
#pragma unroll
  for (int i = 0; i < 4; ++i) {
    off[t * 4 + i] = a;
    lcnt[t * 4 + i] = a;
    a += loc[i];
  }
  if (t == 1023) off[4096] = a;
  __syncthreads();

  for (int e = t; e < NEDGE; e += 1024) {
    int d = ei[NEDGE + e];
    int pos = atomicAdd(&lcnt[d], 1);
    EdgeRec r;
    r.src = ei[e];
    r.a0 = ea[2 * e];
    r.a1 = ea[2 * e + 1];
    r.pad = 0;
    er[pos] = r;
  }
}

// ---------------------------------------------------------------------------
// GINE aggregation via packed-edge CSR gather; emits split(x+agg).
struct AggJob {
  const _Float16* xh; const _Float16* xl; const EdgeRec* er;
  const int* off; const float* we; const float* be;
  _Float16* sh; _Float16* sl;
};

__global__ __launch_bounds__(256) void k_agg2(AggJob a0, AggJob a1) {
  const AggJob& a = blockIdx.y ? a1 : a0;
  const int n = blockIdx.x;
  const int c = threadIdx.x;
  const float w0 = a.we[c], w1 = a.we[HDIM + c], bb = a.be[c];
  const int j0 = a.off[n], j1 = a.off[n + 1];
  float sum = 0.f;
  int j = j0;
  for (; j + 1 < j1; j += 2) {
    EdgeRec ra = a.er[j];
    EdgeRec rb = a.er[j + 1];
    float xa = (float)a.xh[(size_t)ra.src * HDIM + c] + (float)a.xl[(size_t)ra.src * HDIM + c];
    float xb = (float)a.xh[(size_t)rb.src * HDIM + c] + (float)a.xl[(size_t)rb.src * HDIM + c];
    sum += fmaxf(xa + ra.a0 * w0 + ra.a1 * w1 + bb, 0.f);
    sum += fmaxf(xb + rb.a0 * w0 + rb.a1 * w1 + bb, 0.f);
  }
  if (j < j1) {
    EdgeRec ra = a.er[j];
    float xa = (float)a.xh[(size_t)ra.src * HDIM + c] + (float)a.xl[(size_t)ra.src * HDIM + c];
    sum += fmaxf(xa + ra.a0 * w0 + ra.a1 * w1 + bb, 0.f);
  }
  float self = (float)a.xh[(size_t)n * HDIM + c] + (float)a.xl[(size_t)n * HDIM + c];
  _Float16 h, l;
  splitf(self + sum, h, l);
  a.sh[(size_t)n * HDIM + c] = h;
  a.sl[(size_t)n * HDIM + c] = l;
}

// ---------------------------------------------------------------------------
// Fused GINE layer: t1 = relu(A@W1+b1) kept in LDS, out = relu(t1@W2+b2).
// 32 rows/block, 4 waves = 4 col-quadrants (each wave owns its W tile -> the
// k-loops are barrier-free). Grid (128 row-tiles, 2 graphs). LDS 108 KB.
struct FusedJob {
  const _Float16* Ah; const _Float16* Al;
  const _Float16* W1h; const _Float16* W1l; const float* b1;
  const _Float16* W2h; const _Float16* W2l; const float* b2;
  _Float16* Oh; _Float16* Ol;
};

__global__ __launch_bounds__(256) void k_gine_fused(FusedJob j0, FusedJob j1) {
  const FusedJob J = blockIdx.y ? j1 : j0;
  __shared__ _Float16 Bh[4][64][72], Bl[4][64][72];        // per-wave W tile
  __shared__ _Float16 Ast_h[4][32][72], Ast_l[4][32][72];  // A, then t1
  const int t = threadIdx.x;
  const int bm = blockIdx.x * 32;
  const int lane = t & 63, w = t >> 6;
  const int l15 = lane & 15, l4 = lane >> 4;

  // stage full A (32 rows x 256 k, both planes)
#pragma unroll
  for (int rep = 0; rep < 4; ++rep) {
    int idx = t + rep * 256;       // 0..1023
    int r = idx >> 5;              // row
    int c8 = idx & 31;             // k-chunk
    size_t off = (size_t)(bm + r) * 256 + c8 * 8;
    *(f16x8*)&Ast_h[c8 >> 3][r][(c8 & 7) * 8] = *(const f16x8*)&J.Ah[off];
    *(f16x8*)&Ast_l[c8 >> 3][r][(c8 & 7) * 8] = *(const f16x8*)&J.Al[off];
  }
  __syncthreads();

  f32x4 acc[2][4] = {};
  // ---- GEMM1 ----
  for (int k0 = 0; k0 < 4; ++k0) {
#pragma unroll
    for (int rep = 0; rep < 8; ++rep) {
      int idx = lane + rep * 64;
      int nr = idx >> 3, c8 = idx & 7;
      size_t off = (size_t)(w * 64 + nr) * 256 + k0 * 64 + c8 * 8;
      *(f16x8*)&Bh[w][nr][c8 * 8] = *(const f16x8*)&J.W1h[off];
      *(f16x8*)&Bl[w][nr][c8 * 8] = *(const f16x8*)&J.W1l[off];
    }
#pragma unroll
    for (int kh = 0; kh < 2; ++kh) {
      f16x8 a0h = *(f16x8*)&Ast_h[k0][l15][kh * 32 + l4 * 8];
      f16x8 a0l = *(f16x8*)&Ast_l[k0][l15][kh * 32 + l4 * 8];
      f16x8 a1h = *(f16x8*)&Ast_h[k0][16 + l15][kh * 32 + l4 * 8];
      f16x8 a1l = *(f16x8*)&Ast_l[k0][16 + l15][kh * 32 + l4 * 8];
#pragma unroll
      for (int ni = 0; ni < 4; ++ni) {
        f16x8 bh = *(f16x8*)&Bh[w][ni * 16 + l15][kh * 32 + l4 * 8];
        f16x8 bl = *(f16x8*)&Bl[w][ni * 16 + l15][kh * 32 + l4 * 8];
        acc[0][ni] = __builtin_amdgcn_mfma_f32_16x16x32_f16(a0h, bh, acc[0][ni], 0, 0, 0);
        acc[0][ni] = __builtin_amdgcn_mfma_f32_16x16x32_f16(a0h, bl, acc[0][ni], 0, 0, 0);
        acc[0][ni] = __builtin_amdgcn_mfma_f32_16x16x32_f16(a0l, bh, acc[0][ni], 0, 0, 0);
        acc[1][ni] = __builtin_amdgcn_mfma_f32_16x16x32_f16(a1h, bh, acc[1][ni], 0, 0, 0);
        acc[1][ni] = __builtin_amdgcn_mfma_f32_16x16x32_f16(a1h, bl, acc[1][ni], 0, 0, 0);
        acc[1][ni] = __builtin_amdgcn_mfma_f32_16x16x32_f16(a1l, bh, acc[1][ni], 0, 0, 0);
      }
    }
  }
  __syncthreads();  // all waves done reading A before t1 overwrite
  // epilogue -> t1 in LDS (kblk = w)
#pragma unroll
  for (int mi = 0; mi < 2; ++mi)
#pragma unroll
    for (int ni = 0; ni < 4; ++ni) {
      int cl = ni * 16 + l15;
      float bv = J.b1[w * 64 + cl];
#pragma unroll
      for (int r = 0; r < 4; ++r) {
        int row = mi * 16 + l4 * 4 + r;
        float v = fmaxf(acc[mi][ni][r] + bv, 0.f);
        _Float16 hh, ll;
        splitf(v, hh, ll);
        Ast_h[w][row][cl] = hh;
        Ast_l[w][row][cl] = ll;
      }
    }
  __syncthreads();  // t1 complete

  // ---- GEMM2 ----
#pragma unroll
  for (int mi = 0; mi < 2; ++mi)
#pragma unroll
    for (int ni = 0; ni < 4; ++ni) acc[mi][ni] = (f32x4){0.f, 0.f, 0.f, 0.f};
  for (int k0 = 0; k0 < 4; ++k0) {
#pragma unroll
    for (int rep = 0; rep < 8; ++rep) {
      int idx = lane + rep * 64;
      int nr = idx >> 3, c8 = idx & 7;
      size_t off = (size_t)(w * 64 + nr) * 256 + k0 * 64 + c8 * 8;
      *(f16x8*)&Bh[w][nr][c8 * 8] = *(const f16x8*)&J.W2h[off];
      *(f16x8*)&Bl[w][nr][c8 * 8] = *(const f16x8*)&J.W2l[off];
    }
#pragma unroll
    for (int kh = 0; kh < 2; ++kh) {
      f16x8 a0h = *(f16x8*)&Ast_h[k0][l15][kh * 32 + l4 * 8];
      f16x8 a0l = *(f16x8*)&Ast_l[k0][l15][kh * 32 + l4 * 8];
      f16x8 a1h = *(f16x8*)&Ast_h[k0][16 + l15][kh * 32 + l4 * 8];
      f16x8 a1l = *(f16x8*)&Ast_l[k0][16 + l15][kh * 32 + l4 * 8];
#pragma unroll
      for (int ni = 0; ni < 4; ++ni) {
        f16x8 bh = *(f16x8*)&Bh[w][ni * 16 + l15][kh * 32 + l4 * 8];
        f16x8 bl = *(f16x8*)&Bl[w][ni * 16 + l15][kh * 32 + l4 * 8];
        acc[0][ni] = __builtin_amdgcn_mfma_f32_16x16x32_f16(a0h, bh, acc[0][ni], 0, 0, 0);
        acc[0][ni] = __builtin_amdgcn_mfma_f32_16x16x32_f16(a0h, bl, acc[0][ni], 0, 0, 0);
        acc[0][ni] = __builtin_amdgcn_mfma_f32_16x16x32_f16(a0l, bh, acc[0][ni], 0, 0, 0);
        acc[1][ni] = __builtin_amdgcn_mfma_f32_16x16x32_f16(a1h, bh, acc[1][ni], 0, 0, 0);
        acc[1][ni] = __builtin_amdgcn_mfma_f32_16x16x32_f16(a1h, bl, acc[1][ni], 0, 0, 0);
        acc[1][ni] = __builtin_amdgcn_mfma_f32_16x16x32_f16(a1l, bh, acc[1][ni], 0, 0, 0);
      }
    }
  }
#pragma unroll
  for (int mi = 0; mi < 2; ++mi)
#pragma unroll
    for (int ni = 0; ni < 4; ++ni) {
      int col = w * 64 + ni * 16 + l15;
      float bv = J.b2[col];
#pragma unroll
      for (int r = 0; r < 4; ++r) {
        int row = bm + mi * 16 + l4 * 4 + r;
        float v = fmaxf(acc[mi][ni][r] + bv, 0.f);
        _Float16 hh, ll;
        splitf(v, hh, ll);
        J.Oh[(size_t)row * 256 + col] = hh;
        J.Ol[(size_t)row * 256 + col] = ll;
      }
    }
}

// ---------------------------------------------------------------------------
// Unified split-f16 MFMA GEMM for QKV, K=256, job table indexed by blockIdx.z.
// outmode = flags>>4: 1 = split planes (scaled); 3 = transposed f16-hi Vt.
struct GJob {
  const _Float16* Ah; const _Float16* Al;
  const _Float16* Bh; const _Float16* Bl;
  const float* bias;
  _Float16* Ch; _Float16* Cl; _Float16* Vt;
  float oscale; int flags;
};
struct GJobs { GJob j[6]; };

__global__ __launch_bounds__(256) void k_gemm(GJobs js) {
  const GJob J = js.j[blockIdx.z];
  const int relu = J.flags & 1;
  const int outmode = J.flags >> 4;
  __shared__ _Float16 Ah[64][72], Al[64][72], Bh[64][72], Bl[64][72];
  const int t = threadIdx.x;
  const int bm = blockIdx.x * 64, bn = blockIdx.y * 64;
  const int lane = t & 63, w = t >> 6;
  const int l15 = lane & 15, l4 = lane >> 4;
  const int wm = (w >> 1) * 32, wn = (w & 1) * 32;
  f32x4 acc[2][2] = {};
  for (int k0 = 0; k0 < 256; k0 += 64) {
    __syncthreads();
#pragma unroll
    for (int rep = 0; rep < 2; ++rep) {
      int idx = t + rep * 256;
      int r = idx >> 3, k8 = (idx & 7) * 8;
      size_t offa = (size_t)(bm + r) * 256 + k0 + k8;
      *(f16x8*)&Ah[r][k8] = *(const f16x8*)&J.Ah[offa];
      *(f16x8*)&Al[r][k8] = *(const f16x8*)&J.Al[offa];
      size_t offb = (size_t)(bn + r) * 256 + k0 + k8;
      *(f16x8*)&Bh[r][k8] = *(const f16x8*)&J.Bh[offb];
      *(f16x8*)&Bl[r][k8] = *(const f16x8*)&J.Bl[offb];
    }
    __syncthreads();
#pragma unroll
    for (int kh = 0; kh < 2; ++kh) {
      f16x8 a0h = *(f16x8*)&Ah[wm + l15][kh * 32 + l4 * 8];
      f16x8 a0l = *(f16x8*)&Al[wm + l15][kh * 32 + l4 * 8];
      f16x8 a1h = *(f16x8*)&Ah[wm + 16 + l15][kh * 32 + l4 * 8];
      f16x8 a1l = *(f16x8*)&Al[wm + 16 + l15][kh * 32 + l4 * 8];
      f16x8 b0h = *(f16x8*)&Bh[wn + l15][kh * 32 + l4 * 8];
      f16x8 b0l = *(f16x8*)&Bl[wn + l15][kh * 32 + l4 * 8];
      f16x8 b1h = *(f16x8*)&Bh[wn + 16 + l15][kh * 32 + l4 * 8];
      f16x8 b1l = *(f16x8*)&Bl[wn + 16 + l15][kh * 32 + l4 * 8];
      acc[0][0] = __builtin_amdgcn_mfma_f32_16x16x32_f16(a0h, b0h, acc[0][0], 0, 0, 0);
      acc[0][0] = __builtin_amdgcn_mfma_f32_16x16x32_f16(a0h, b0l, acc[0][0], 0, 0, 0);
      acc[0][0] = __builtin_amdgcn_mfma_f32_16x16x32_f16(a0l, b0h, acc[0][0], 0, 0, 0);
      acc[0][1] = __builtin_amdgcn_mfma_f32_16x16x32_f16(a0h, b1h, acc[0][1], 0, 0, 0);
      acc[0][1] = __builtin_amdgcn_mfma_f32_16x16x32_f16(a0h, b1l, acc[0][1], 0, 0, 0);
      acc[0][1] = __builtin_amdgcn_mfma_f32_16x16x32_f16(a0l, b1h, acc[0][1], 0, 0, 0);
      acc[1][0] = __builtin_amdgcn_mfma_f32_16x16x32_f16(a1h, b0h, acc[1][0], 0, 0, 0);
      acc[1][0] = __builtin_amdgcn_mfma_f32_16x16x32_f16(a1h, b0l, acc[1][0], 0, 0, 0);
      acc[1][0] = __builtin_amdgcn_mfma_f32_16x16x32_f16(a1l, b0h, acc[1][0], 0, 0, 0);
      acc[1][1] = __builtin_amdgcn_mfma_f32_16x16x32_f16(a1h, b1h, acc[1][1], 0, 0, 0);
      acc[1][1] = __builtin_amdgcn_mfma_f32_16x16x32_f16(a1h, b1l, acc[1][1], 0, 0, 0);
      acc[1][1] = __builtin_amdgcn_mfma_f32_16x16x32_f16(a1l, b1h, acc[1][1], 0, 0, 0);
    }
  }
  if (outmode == 3) __syncthreads();
#pragma unroll
  for (int mi = 0; mi < 2; ++mi)
#pragma unroll
    for (int ni = 0; ni < 2; ++ni) {
      int col = bn + wn + ni * 16 + l15;
      float bv = J.bias[col];
#pragma unroll
      for (int r = 0; r < 4; ++r) {
        int row = bm + wm + mi * 16 + l4 * 4 + r;
        float v = acc[mi][ni][r] + bv;
        if (relu) v = fmaxf(v, 0.f);
        if (outmode == 1) {
          float vs = v * J.oscale;
          _Float16 hh, ll;
          splitf(vs, hh, ll);
          J.Ch[(size_t)row * 256 + col] = hh;
          J.Cl[(size_t)row * 256 + col] = ll;
        } else {
          Ah[wn + ni * 16 + l15][wm + mi * 16 + l4 * 4 + r] = (_Float16)v;
        }
      }
    }
  if (outmode == 3) {
    __syncthreads();
#pragma unroll
    for (int rep = 0; rep < 2; ++rep) {
      int idx = t + rep * 256;
      int d = idx >> 3, n8 = (idx & 7) * 8;
      *(f16x8*)&J.Vt[(size_t)(bn + d) * 4096 + bm + n8] = *(f16x8*)&Ah[d][n8];
    }
  }
}

// ---------------------------------------------------------------------------
// Swapped-QK flash attention, 128 q/block, quarter k-split.
// Grid (32 q-tiles, dir*4+head, 4 quarters) = 1024 blocks, 3 blocks/CU.
struct AttnArgs {
  const _Float16* Qh[2]; const _Float16* Ql[2];
  const _Float16* Kh[2]; const _Float16* Kl[2];
  const _Float16* Vth[2];
  _Float16* Opart; float* mpart; float* lpart;
};

__global__ __launch_bounds__(256) void k_attn6(AttnArgs A, int nkq) {
  __shared__ _Float16 Ksh[64][72], Ksl[64][72];
  __shared__ _Float16 Vsh[64][72];
  __shared__ _Float16 Psh[4][32][72];
  const int t = threadIdx.x;
  const int dir = blockIdx.y >> 2, h = blockIdx.y & 3;
  const int q0 = blockIdx.x * 128;
  const int quarter = blockIdx.z;
  const int kbase = quarter * nkq;
  const int lane = t & 63, w = t >> 6;
  const int l15 = lane & 15, l4 = lane >> 4;
  const int qw = q0 + w * 32;

  const _Float16* Qh_g = A.Qh[dir];
  const _Float16* Ql_g = A.Ql[dir];
  const _Float16* Kh_g = A.Kh[dir];
  const _Float16* Kl_g = A.Kl[dir];
  const _Float16* Vth_g = A.Vth[dir];

  f16x8 qh[2][2], ql[2][2];
#pragma unroll
  for (int qf = 0; qf < 2; ++qf) {
    size_t qoff = (size_t)(qw + qf * 16 + l15) * 256 + h * 64;
#pragma unroll
    for (int kh = 0; kh < 2; ++kh) {
      qh[qf][kh] = *(const f16x8*)&Qh_g[qoff + kh * 32 + l4 * 8];
      ql[qf][kh] = *(const f16x8*)&Ql_g[qoff + kh * 32 + l4 * 8];
    }
  }
  f32x4 o[2][4] = {};
  float mrun[2] = {-1e30f, -1e30f};
  float lrun[2] = {0.f, 0.f};

  for (int kt = 0; kt < nkq; kt += 64) {
    const int k0 = kbase + kt;
    __syncthreads();
#pragma unroll
    for (int rep = 0; rep < 2; ++rep) {
      int idx = t + rep * 256;
      int r = idx >> 3, c8 = idx & 7;
      size_t koff = (size_t)(k0 + r) * 256 + h * 64 + c8 * 8;
      *(f16x8*)&Ksh[r][c8 * 8] = *(const f16x8*)&Kh_g[koff];
      *(f16x8*)&Ksl[r][c8 * 8] = *(const f16x8*)&Kl_g[koff];
      int sc = c8 ^ ((r >> 3) & 7);
      size_t voff = (size_t)(h * 64 + r) * 4096 + k0 + c8 * 8;
      *(f16x8*)&Vsh[r][sc * 8] = *(const f16x8*)&Vth_g[voff];
    }
    __syncthreads();

    f32x4 sf[2][4] = {};
#pragma unroll
    for (int kc = 0; kc < 4; ++kc) {
      f16x8 kf0h = *(f16x8*)&Ksh[kc * 16 + l15][l4 * 8];
      f16x8 kf0l = *(f16x8*)&Ksl[kc * 16 + l15][l4 * 8];
      f16x8 kf1h = *(f16x8*)&Ksh[kc * 16 + l15][32 + l4 * 8];
      f16x8 kf1l = *(f16x8*)&Ksl[kc * 16 + l15][32 + l4 * 8];
#pragma unroll
      for (int qf = 0; qf < 2; ++qf) {
        sf[qf][kc] = __builtin_amdgcn_mfma_f32_16x16x32_f16(kf0h, qh[qf][0], sf[qf][kc], 0, 0, 0);
        sf[qf][kc] = __builtin_amdgcn_mfma_f32_16x16x32_f16(kf0h, ql[qf][0], sf[qf][kc], 0, 0, 0);
        sf[qf][kc] = __builtin_amdgcn_mfma_f32_16x16x32_f16(kf0l, qh[qf][0], sf[qf][kc], 0, 0, 0);
        sf[qf][kc] = __builtin_amdgcn_mfma_f32_16x16x32_f16(kf1h, qh[qf][1], sf[qf][kc], 0, 0, 0);
        sf[qf][kc] = __builtin_amdgcn_mfma_f32_16x16x32_f16(kf1h, ql[qf][1], sf[qf][kc], 0, 0, 0);
        sf[qf][kc] = __builtin_amdgcn_mfma_f32_16x16x32_f16(kf1l, qh[qf][1], sf[qf][kc], 0, 0, 0);
      }
    }

#pragma unroll
    for (int qf = 0; qf < 2; ++qf) {
      float mt = -1e30f;
#pragma unroll
      for (int kc = 0; kc < 4; ++kc) {
        float a = fmaxf(fmaxf(sf[qf][kc][0], sf[qf][kc][1]),
                        fmaxf(sf[qf][kc][2], sf[qf][kc][3]));
        mt = fmaxf(mt, a);
      }
      mt = fmaxf(mt, __shfl_xor(mt, 16, 64));
      mt = fmaxf(mt, __shfl_xor(mt, 32, 64));
      float mn = fmaxf(mrun[qf], mt);
      float alpha = __expf(mrun[qf] - mn);
      mrun[qf] = mn;
      float rs = 0.f;
#pragma unroll
      for (int kc = 0; kc < 4; ++kc) {
        float p0 = __expf(sf[qf][kc][0] - mn);
        float p1 = __expf(sf[qf][kc][1] - mn);
        float p2 = __expf(sf[qf][kc][2] - mn);
        float p3 = __expf(sf[qf][kc][3] - mn);
        rs += (p0 + p1) + (p2 + p3);
        f16x4 pv = {(_Float16)p0, (_Float16)p1, (_Float16)p2, (_Float16)p3};
        *(f16x4*)&Psh[w][qf * 16 + l15][kc * 16 + 4 * l4] = pv;
      }
      rs += __shfl_xor(rs, 16, 64);
      rs += __shfl_xor(rs, 32, 64);
      lrun[qf] = lrun[qf] * alpha + rs;
#pragma unroll
      for (int r = 0; r < 4; ++r) {
        float ar = __shfl(alpha, 4 * l4 + r, 64);
        o[qf][0][r] *= ar; o[qf][1][r] *= ar;
        o[qf][2][r] *= ar; o[qf][3][r] *= ar;
      }
    }

#pragma unroll
    for (int kh = 0; kh < 2; ++kh) {
      f16x8 pa0 = *(f16x8*)&Psh[w][l15][kh * 32 + l4 * 8];
      f16x8 pa1 = *(f16x8*)&Psh[w][16 + l15][kh * 32 + l4 * 8];
#pragma unroll
      for (int oc = 0; oc < 4; ++oc) {
        int d = oc * 16 + l15;
        int chunk = (kh * 4 + l4) ^ ((d >> 3) & 7);
        f16x8 vb = *(f16x8*)&Vsh[d][chunk * 8];
        o[0][oc] = __builtin_amdgcn_mfma_f32_16x16x32_f16(pa0, vb, o[0][oc], 0, 0, 0);
        o[1][oc] = __builtin_amdgcn_mfma_f32_16x16x32_f16(pa1, vb, o[1][oc], 0, 0, 0);
      }
    }
  }

  const int slot = dir * 4 + quarter;
#pragma unroll
  for (int qf = 0; qf < 2; ++qf)
#pragma unroll
    for (int oc = 0; oc < 4; ++oc) {
      int col = h * 64 + oc * 16 + l15;
#pragma unroll
      for (int r = 0; r < 4; ++r) {
        int row = qw + qf * 16 + 4 * l4 + r;
        A.Opart[((size_t)slot * 4096 + row) * 256 + col] = (_Float16)o[qf][oc][r];
      }
    }
  if (lane < 16) {
#pragma unroll
    for (int qf = 0; qf < 2; ++qf) {
      int row = qw + qf * 16 + l15;
      A.mpart[(size_t)(slot * 4 + h) * 4096 + row] = mrun[qf];
      A.lpart[(size_t)(slot * 4 + h) * 4096 + row] = lrun[qf];
    }
  }
}

// ---------------------------------------------------------------------------
// Fused combine + residual + segment-mean + fc1 + fc2 + sigmoid.
// One block per graph (batch ids sorted -> contiguous row ranges).
__global__ __launch_bounds__(256) void k_head_all(
    const _Float16* __restrict__ Opart, const float* __restrict__ mpart,
    const float* __restrict__ lpart,
    const _Float16* __restrict__ hmh, const _Float16* __restrict__ hml,
    const _Float16* __restrict__ hph, const _Float16* __restrict__ hpl,
    const int* __restrict__ b_mol, const int* __restrict__ b_prot,
    const float* __restrict__ w1, const float* __restrict__ b1,
    const float* __restrict__ w2, const float* __restrict__ b2,
    float* __restrict__ out) {
  __shared__ float zl[512];
  __shared__ float wsum[4];
  const int g = blockIdx.x;
  const int c = threadIdx.x;
  const int h = c >> 6;
  for (int dir = 0; dir < 2; ++dir) {
    const int* batch = dir ? b_prot : b_mol;
    const _Float16* Hh = dir ? hph : hmh;
    const _Float16* Hl = dir ? hpl : hml;
    int lo = 0, hi = 4096;
    while (lo < hi) { int mid = (lo + hi) >> 1; if (batch[mid] < g) lo = mid + 1; else hi = mid; }
    int start = lo;
    lo = 0; hi = 4096;
    while (lo < hi) { int mid = (lo + hi) >> 1; if (batch[mid] < g + 1) lo = mid + 1; else hi = mid; }
    int end = lo;
    float zacc = 0.f;
    for (int row = start; row < end; ++row) {
      float mv[4], lv[4], M = -1e30f;
#pragma unroll
      for (int q = 0; q < 4; ++q) {
        int slot = dir * 4 + q;
        mv[q] = mpart[(size_t)(slot * 4 + h) * 4096 + row];
        lv[q] = lpart[(size_t)(slot * 4 + h) * 4096 + row];
        M = fmaxf(M, mv[q]);
      }
      float L = 0.f, acc = 0.f;
#pragma unroll
      for (int q = 0; q < 4; ++q) {
        float e = __expf(mv[q] - M);
        L += lv[q] * e;
        acc += (float)Opart[((size_t)(dir * 4 + q) * 4096 + row) * 256 + c] * e;
      }
      float hin = (float)Hh[(size_t)row * 256 + c] + (float)Hl[(size_t)row * 256 + c];
      zacc += acc / L + hin;
    }
    zl[dir * 256 + c] = zacc / fmaxf((float)(end - start), 1.0f);
  }
  __syncthreads();
  float acc = b1[c];
  for (int k = 0; k < 512; ++k) acc += zl[k] * w1[k * HDIM + c];
  acc = fmaxf(acc, 0.f);
  float p = acc * w2[c];
#pragma unroll
  for (int off = 1; off < 64; off <<= 1) p += __shfl_xor(p, off, 64);
  if ((c & 63) == 0) wsum[c >> 6] = p;
  __syncthreads();
  if (c == 0) {
    float s = (wsum[0] + wsum[1]) + (wsum[2] + wsum[3]) + b2[0];
    out[g] = 1.0f / (1.0f + __expf(-s));
  }
}

// ---------------------------------------------------------------------------
extern "C" void kernel_launch(void* const* d_in, const int* in_sizes, int n_in,
                              void* d_out, int out_size, void* d_ws, size_t ws_size,
                              hipStream_t stream) {
  const float* x_mol   = (const float*)d_in[0];
  const float* x_prot  = (const float*)d_in[1];
  const float* ea_mol  = (const float*)d_in[2];
  const float* ea_prot = (const float*)d_in[3];
  const int*   ei_mol  = (const int*)d_in[4];
  const int*   ei_prot = (const int*)d_in[5];
  const int*   b_mol   = (const int*)d_in[6];
  const int*   b_prot  = (const int*)d_in[7];
  const float* nlm_w = (const float*)d_in[8];
  const float* nlm_b = (const float*)d_in[9];
  const float* nlp_w = (const float*)d_in[10];
  const float* nlp_b = (const float*)d_in[11];
  const float* elm_w = (const float*)d_in[12];
  const float* elm_b = (const float*)d_in[13];
  const float* elp_w = (const float*)d_in[14];
  const float* elp_b = (const float*)d_in[15];
  const float* mol_w1 = (const float*)d_in[16];
  const float* mol_b1 = (const float*)d_in[17];
  const float* mol_w2 = (const float*)d_in[18];
  const float* mol_b2 = (const float*)d_in[19];
  const float* prot_w1 = (const float*)d_in[20];
  const float* prot_b1 = (const float*)d_in[21];
  const float* prot_w2 = (const float*)d_in[22];
  const float* prot_b2 = (const float*)d_in[23];
  const float* mp_wq = (const float*)d_in[24];
  const float* mp_bq = (const float*)d_in[25];
  const float* mp_wk = (const float*)d_in[26];
  const float* mp_bk = (const float*)d_in[27];
  const float* mp_wv = (const float*)d_in[28];
  const float* mp_bv = (const float*)d_in[29];
  const float* pm_wq = (const float*)d_in[30];
  const float* pm_bq = (const float*)d_in[31];
  const float* pm_wk = (const float*)d_in[32];
  const float* pm_bk = (const float*)d_in[33];
  const float* pm_wv = (const float*)d_in[34];
  const float* pm_bv = (const float*)d_in[35];
  const float* fc1_w = (const float*)d_in[36];
  const float* fc1_b = (const float*)d_in[37];
  const float* fc2_w = (const float*)d_in[38];
  const float* fc2_b = (const float*)d_in[39];
  float* out = (float*)d_out;

  // workspace carve (MB offsets); peak ~60 MB
  char* W8 = (char*)d_ws;
  const size_t MB = 1u << 20;
  _Float16* wtH  = (_Float16*)(W8 + 0 * MB);
  _Float16* wtL  = (_Float16*)(W8 + 2 * MB);
  _Float16* hmh  = (_Float16*)(W8 + 4 * MB);
  _Float16* hml  = (_Float16*)(W8 + 6 * MB);
  _Float16* hph  = (_Float16*)(W8 + 8 * MB);
  _Float16* hpl  = (_Float16*)(W8 + 10 * MB);
  _Float16* amh  = (_Float16*)(W8 + 12 * MB);
  _Float16* aml  = (_Float16*)(W8 + 14 * MB);
  _Float16* aph  = (_Float16*)(W8 + 16 * MB);
  _Float16* apl  = (_Float16*)(W8 + 18 * MB);
  _Float16* Qh0  = (_Float16*)(W8 + 20 * MB);
  _Float16* Ql0  = (_Float16*)(W8 + 22 * MB);
  _Float16* Kh0  = (_Float16*)(W8 + 24 * MB);
  _Float16* Kl0  = (_Float16*)(W8 + 26 * MB);
  _Float16* Qh1  = (_Float16*)(W8 + 28 * MB);
  _Float16* Ql1  = (_Float16*)(W8 + 30 * MB);
  _Float16* Kh1  = (_Float16*)(W8 + 32 * MB);
  _Float16* Kl1  = (_Float16*)(W8 + 34 * MB);
  _Float16* Vth0 = (_Float16*)(W8 + 36 * MB);
  _Float16* Vth1 = (_Float16*)(W8 + 38 * MB);
  _Float16* Opart = (_Float16*)(W8 + 40 * MB);  // 16 MB: [8 slots][4096][256] f16
  float* mpart = (float*)(W8 + 56 * MB);        // 32*4096 floats (512 KB)
  float* lpart = (float*)(W8 + 56 * MB + 512 * 1024);
  int* off_m = (int*)(W8 + 57 * MB);            // 4097 ints
  int* off_p = off_m + 8192;
  EdgeRec* er_m = (EdgeRec*)(W8 + 58 * MB);     // 1 MB
  EdgeRec* er_p = (EdgeRec*)(W8 + 59 * MB);     // 1 MB

  // weights: 0,1 mol_w1 | 2,3 mol_w2 | 4,5 prot_w1 | 6,7 prot_w2
  // 8 mp_wq 9 mp_wk 10 mp_wv | 11 pm_wq 12 pm_wk 13 pm_wv
  PtrPack pk;
  pk.p[0] = mol_w1;           pk.p[1] = mol_w1 + 65536;
  pk.p[2] = mol_w2;           pk.p[3] = mol_w2 + 65536;
  pk.p[4] = prot_w1;          pk.p[5] = prot_w1 + 65536;
  pk.p[6] = prot_w2;          pk.p[7] = prot_w2 + 65536;
  pk.p[8] = mp_wq;  pk.p[9] = mp_wk;  pk.p[10] = mp_wv;
  pk.p[11] = pm_wq; pk.p[12] = pm_wk; pk.p[13] = pm_wv;
  k_prep_wt<<<dim3(4, 4, 14), 256, 0, stream>>>(pk, wtH, wtL);

  k_csr_all<<<2, 1024, 0, stream>>>(ei_mol, ei_prot, ea_mol, ea_prot,
                                    off_m, off_p, er_m, er_p);

  EmbJob em = {x_mol, nlm_w, nlm_b, hmh, hml, 8};
  EmbJob ep = {x_prot, nlp_w, nlp_b, hph, hpl, 4};
  k_node_embed2<<<dim3(NMOL, 2), 256, 0, stream>>>(em, ep);

#define WTH(i) (wtH + (size_t)(i) * 65536)
#define WTL(i) (wtL + (size_t)(i) * 65536)

  AggJob am = {hmh, hml, er_m, off_m, elm_w, elm_b, amh, aml};
  AggJob ap = {hph, hpl, er_p, off_p, elp_w, elp_b, aph, apl};

  for (int l = 0; l < 2; ++l) {
    k_agg2<<<dim3(NMOL, 2), 256, 0, stream>>>(am, ap);
    FusedJob fm = {amh, aml, WTH(l), WTL(l), mol_b1 + l * 256,
                   WTH(2 + l), WTL(2 + l), mol_b2 + l * 256, hmh, hml};
    FusedJob fp = {aph, apl, WTH(4 + l), WTL(4 + l), prot_b1 + l * 256,
                   WTH(6 + l), WTL(6 + l), prot_b2 + l * 256, hph, hpl};
    k_gine_fused<<<dim3(128, 2), 256, 0, stream>>>(fm, fp);
  }

  // QKV for both attention directions, one dispatch (z=6); V transposed in-epilogue
  {
    GJobs q = {};
    q.j[0] = {hmh, hml, WTH(8), WTL(8), mp_bq, Qh0, Ql0, nullptr, 0.125f, 1 << 4};
    q.j[1] = {hph, hpl, WTH(9), WTL(9), mp_bk, Kh0, Kl0, nullptr, 1.0f, 1 << 4};
    q.j[2] = {hph, hpl, WTH(10), WTL(10), mp_bv, nullptr, nullptr, Vth0, 1.0f, 3 << 4};
    q.j[3] = {hph, hpl, WTH(11), WTL(11), pm_bq, Qh1, Ql1, nullptr, 0.125f, 1 << 4};
    q.j[4] = {hmh, hml, WTH(12), WTL(12), pm_bk, Kh1, Kl1, nullptr, 1.0f, 1 << 4};
    q.j[5] = {hmh, hml, WTH(13), WTL(13), pm_bv, nullptr, nullptr, Vth1, 1.0f, 3 << 4};
    k_gemm<<<dim3(64, 4, 6), 256, 0, stream>>>(q);
  }

  AttnArgs aa;
  aa.Qh[0] = Qh0; aa.Ql[0] = Ql0; aa.Kh[0] = Kh0; aa.Kl[0] = Kl0; aa.Vth[0] = Vth0;
  aa.Qh[1] = Qh1; aa.Ql[1] = Ql1; aa.Kh[1] = Kh1; aa.Kl[1] = Kl1; aa.Vth[1] = Vth1;
  aa.Opart = Opart; aa.mpart = mpart; aa.lpart = lpart;
  k_attn6<<<dim3(32, 8, 4), 256, 0, stream>>>(aa, 1024);

  k_head_all<<<NG, 256, 0, stream>>>(Opart, mpart, lpart, hmh, hml, hph, hpl,
                                     b_mol, b_prot, fc1_w, fc1_b, fc2_w, fc2_b, out);
#undef WTH
#undef WTL
}

// Round 12
// 563.707 us; speedup vs baseline: 1.0984x; 1.0984x over previous
//
#include <hip/hip_runtime.h>
#include <math.h>

#define HDIM 256
#define NMOL 4096
#define NPROT 4096
#define NEDGE 65536
#define NG 32

typedef _Float16 f16x8 __attribute__((ext_vector_type(8)));
typedef _Float16 f16x4 __attribute__((ext_vector_type(4)));
typedef __attribute__((ext_vector_type(4))) float f32x4;

__device__ __forceinline__ void splitf(float x, _Float16& h, _Float16& l) {
  h = (_Float16)x;
  l = (_Float16)(x - (float)h);
}

struct __align__(16) EdgeRec { int src; float a0; float a1; int pad; };

// ---------------------------------------------------------------------------
// Transpose + convert 14 H x H fp32 weights into split f16 planes Wt[n][k].
struct PtrPack { const float* p[14]; };

__global__ __launch_bounds__(256) void k_prep_wt(PtrPack pk, _Float16* __restrict__ dh,
                                                 _Float16* __restrict__ dl) {
  __shared__ float Ts[64][68];
  const int m = blockIdx.z;
  const int n0 = blockIdx.y * 64, k0 = blockIdx.x * 64;
  const float* W = pk.p[m];
  const int t = threadIdx.x;
#pragma unroll
  for (int rep = 0; rep < 16; ++rep) {
    int k = rep * 4 + (t >> 6);
    int n = t & 63;
    Ts[n][k] = W[(size_t)(k0 + k) * 256 + n0 + n];
  }
  __syncthreads();
#pragma unroll
  for (int rep = 0; rep < 2; ++rep) {
    int idx = t + rep * 256;
    int nr = idx >> 3, koff = (idx & 7) * 8;
    f16x8 vh, vl;
#pragma unroll
    for (int i = 0; i < 8; ++i) {
      _Float16 h, l;
      splitf(Ts[nr][koff + i], h, l);
      vh[i] = h; vl[i] = l;
    }
    size_t off = (size_t)m * 65536 + (size_t)(n0 + nr) * 256 + k0 + koff;
    *(f16x8*)&dh[off] = vh;
    *(f16x8*)&dl[off] = vl;
  }
}

// ---------------------------------------------------------------------------
// node embedding -> split planes, both graphs per dispatch
struct EmbJob {
  const float* x; const float* w; const float* b;
  _Float16* oh; _Float16* ol; int K;
};

__global__ __launch_bounds__(256) void k_node_embed2(EmbJob j0, EmbJob j1) {
  const EmbJob& j = blockIdx.y ? j1 : j0;
  const int i = blockIdx.x;
  const int c = threadIdx.x;
  float acc = j.b[c];
  for (int k = 0; k < j.K; ++k) acc += j.x[i * j.K + k] * j.w[k * HDIM + c];
  _Float16 h, l;
  splitf(acc, h, l);
  j.oh[(size_t)i * HDIM + c] = h;
  j.ol[(size_t)i * HDIM + c] = l;
}

// ---------------------------------------------------------------------------
// Whole CSR build in ONE dispatch: 2 blocks (one per graph) x 1024 threads.
__global__ __launch_bounds__(1024) void k_csr_all(
    const int* __restrict__ ei0, const int* __restrict__ ei1,
    const float* __restrict__ ea0, const float* __restrict__ ea1,
    int* __restrict__ off0, int* __restrict__ off1,
    EdgeRec* __restrict__ er0, EdgeRec* __restrict__ er1) {
  __shared__ int lcnt[4096];
  __shared__ int wbase[16];
  const int dir = blockIdx.x;
  const int* ei = dir ? ei1 : ei0;
  const float* ea = dir ? ea1 : ea0;
  int* off = dir ? off1 : off0;
  EdgeRec* er = dir ? er1 : er0;
  const int t = threadIdx.x;
  const int lane = t & 63, wv = t >> 6;

#pragma unroll
  for (int i = 0; i < 4; ++i) lcnt[t + i * 1024] = 0;
  __syncthreads();
  for (int e = t; e < NEDGE; e += 1024) atomicAdd(&lcnt[ei[NEDGE + e]], 1);
  __syncthreads();

  int loc[4], s = 0;
#pragma unroll
  for (int i = 0; i < 4; ++i) { loc[i] = lcnt[t * 4 + i]; s += loc[i]; }
  int pre = s;
#pragma unroll
  for (int o = 1; o < 64; o <<= 1) {
    int v = __shfl_up(pre, o, 64);
    if (lane >= o) pre += v;
  }
  if (lane == 63) wbase[wv] = pre;
  __syncthreads();
  if (t == 0) {
    int a = 0;
    for (int i = 0; i < 16; ++i) { int v = wbase[i]; wbase[i] = a; a += v; }
  }
  __syncthreads();
  int a = wbase[wv] + pre - s;
#pragma unroll
  for (int i = 0; i < 4; ++i) {
    off[t * 4 + i] = a;
    lcnt[t * 4 + i] = a;
    a += loc[i];
  }
  if (t == 1023) off[4096] = a;
  __syncthreads();

  for (int e = t; e < NEDGE; e += 1024) {
    int d = ei[NEDGE + e];
    int pos = atomicAdd(&lcnt[d], 1);
    EdgeRec r;
    r.src = ei[e];
    r.a0 = ea[2 * e];
    r.a1 = ea[2 * e + 1];
    r.pad = 0;
    er[pos] = r;
  }
}

// ---------------------------------------------------------------------------
// GINE aggregation via packed-edge CSR gather; emits split(x+agg).
struct AggJob {
  const _Float16* xh; const _Float16* xl; const EdgeRec* er;
  const int* off; const float* we; const float* be;
  _Float16* sh; _Float16* sl;
};

__global__ __launch_bounds__(256) void k_agg2(AggJob a0, AggJob a1) {
  const AggJob& a = blockIdx.y ? a1 : a0;
  const int n = blockIdx.x;
  const int c = threadIdx.x;
  const float w0 = a.we[c], w1 = a.we[HDIM + c], bb = a.be[c];
  const int j0 = a.off[n], j1 = a.off[n + 1];
  float sum = 0.f;
  int j = j0;
  for (; j + 1 < j1; j += 2) {
    EdgeRec ra = a.er[j];
    EdgeRec rb = a.er[j + 1];
    float xa = (float)a.xh[(size_t)ra.src * HDIM + c] + (float)a.xl[(size_t)ra.src * HDIM + c];
    float xb = (float)a.xh[(size_t)rb.src * HDIM + c] + (float)a.xl[(size_t)rb.src * HDIM + c];
    sum += fmaxf(xa + ra.a0 * w0 + ra.a1 * w1 + bb, 0.f);
    sum += fmaxf(xb + rb.a0 * w0 + rb.a1 * w1 + bb, 0.f);
  }
  if (j < j1) {
    EdgeRec ra = a.er[j];
    float xa = (float)a.xh[(size_t)ra.src * HDIM + c] + (float)a.xl[(size_t)ra.src * HDIM + c];
    sum += fmaxf(xa + ra.a0 * w0 + ra.a1 * w1 + bb, 0.f);
  }
  float self = (float)a.xh[(size_t)n * HDIM + c] + (float)a.xl[(size_t)n * HDIM + c];
  _Float16 h, l;
  splitf(self + sum, h, l);
  a.sh[(size_t)n * HDIM + c] = h;
  a.sl[(size_t)n * HDIM + c] = l;
}

// ---------------------------------------------------------------------------
// Fused GINE layer: t1 = relu(A@W1+b1) in LDS, out = relu(t1@W2+b2).
struct FusedJob {
  const _Float16* Ah; const _Float16* Al;
  const _Float16* W1h; const _Float16* W1l; const float* b1;
  const _Float16* W2h; const _Float16* W2l; const float* b2;
  _Float16* Oh; _Float16* Ol;
};

__global__ __launch_bounds__(256) void k_gine_fused(FusedJob j0, FusedJob j1) {
  const FusedJob J = blockIdx.y ? j1 : j0;
  __shared__ _Float16 Bh[4][64][72], Bl[4][64][72];
  __shared__ _Float16 Ast_h[4][32][72], Ast_l[4][32][72];
  const int t = threadIdx.x;
  const int bm = blockIdx.x * 32;
  const int lane = t & 63, w = t >> 6;
  const int l15 = lane & 15, l4 = lane >> 4;

#pragma unroll
  for (int rep = 0; rep < 4; ++rep) {
    int idx = t + rep * 256;
    int r = idx >> 5;
    int c8 = idx & 31;
    size_t off = (size_t)(bm + r) * 256 + c8 * 8;
    *(f16x8*)&Ast_h[c8 >> 3][r][(c8 & 7) * 8] = *(const f16x8*)&J.Ah[off];
    *(f16x8*)&Ast_l[c8 >> 3][r][(c8 & 7) * 8] = *(const f16x8*)&J.Al[off];
  }
  __syncthreads();

  f32x4 acc[2][4] = {};
  for (int k0 = 0; k0 < 4; ++k0) {
#pragma unroll
    for (int rep = 0; rep < 8; ++rep) {
      int idx = lane + rep * 64;
      int nr = idx >> 3, c8 = idx & 7;
      size_t off = (size_t)(w * 64 + nr) * 256 + k0 * 64 + c8 * 8;
      *(f16x8*)&Bh[w][nr][c8 * 8] = *(const f16x8*)&J.W1h[off];
      *(f16x8*)&Bl[w][nr][c8 * 8] = *(const f16x8*)&J.W1l[off];
    }
#pragma unroll
    for (int kh = 0; kh < 2; ++kh) {
      f16x8 a0h = *(f16x8*)&Ast_h[k0][l15][kh * 32 + l4 * 8];
      f16x8 a0l = *(f16x8*)&Ast_l[k0][l15][kh * 32 + l4 * 8];
      f16x8 a1h = *(f16x8*)&Ast_h[k0][16 + l15][kh * 32 + l4 * 8];
      f16x8 a1l = *(f16x8*)&Ast_l[k0][16 + l15][kh * 32 + l4 * 8];
#pragma unroll
      for (int ni = 0; ni < 4; ++ni) {
        f16x8 bh = *(f16x8*)&Bh[w][ni * 16 + l15][kh * 32 + l4 * 8];
        f16x8 bl = *(f16x8*)&Bl[w][ni * 16 + l15][kh * 32 + l4 * 8];
        acc[0][ni] = __builtin_amdgcn_mfma_f32_16x16x32_f16(a0h, bh, acc[0][ni], 0, 0, 0);
        acc[0][ni] = __builtin_amdgcn_mfma_f32_16x16x32_f16(a0h, bl, acc[0][ni], 0, 0, 0);
        acc[0][ni] = __builtin_amdgcn_mfma_f32_16x16x32_f16(a0l, bh, acc[0][ni], 0, 0, 0);
        acc[1][ni] = __builtin_amdgcn_mfma_f32_16x16x32_f16(a1h, bh, acc[1][ni], 0, 0, 0);
        acc[1][ni] = __builtin_amdgcn_mfma_f32_16x16x32_f16(a1h, bl, acc[1][ni], 0, 0, 0);
        acc[1][ni] = __builtin_amdgcn_mfma_f32_16x16x32_f16(a1l, bh, acc[1][ni], 0, 0, 0);
      }
    }
  }
  __syncthreads();
#pragma unroll
  for (int mi = 0; mi < 2; ++mi)
#pragma unroll
    for (int ni = 0; ni < 4; ++ni) {
      int cl = ni * 16 + l15;
      float bv = J.b1[w * 64 + cl];
#pragma unroll
      for (int r = 0; r < 4; ++r) {
        int row = mi * 16 + l4 * 4 + r;
        float v = fmaxf(acc[mi][ni][r] + bv, 0.f);
        _Float16 hh, ll;
        splitf(v, hh, ll);
        Ast_h[w][row][cl] = hh;
        Ast_l[w][row][cl] = ll;
      }
    }
  __syncthreads();

#pragma unroll
  for (int mi = 0; mi < 2; ++mi)
#pragma unroll
    for (int ni = 0; ni < 4; ++ni) acc[mi][ni] = (f32x4){0.f, 0.f, 0.f, 0.f};
  for (int k0 = 0; k0 < 4; ++k0) {
#pragma unroll
    for (int rep = 0; rep < 8; ++rep) {
      int idx = lane + rep * 64;
      int nr = idx >> 3, c8 = idx & 7;
      size_t off = (size_t)(w * 64 + nr) * 256 + k0 * 64 + c8 * 8;
      *(f16x8*)&Bh[w][nr][c8 * 8] = *(const f16x8*)&J.W2h[off];
      *(f16x8*)&Bl[w][nr][c8 * 8] = *(const f16x8*)&J.W2l[off];
    }
#pragma unroll
    for (int kh = 0; kh < 2; ++kh) {
      f16x8 a0h = *(f16x8*)&Ast_h[k0][l15][kh * 32 + l4 * 8];
      f16x8 a0l = *(f16x8*)&Ast_l[k0][l15][kh * 32 + l4 * 8];
      f16x8 a1h = *(f16x8*)&Ast_h[k0][16 + l15][kh * 32 + l4 * 8];
      f16x8 a1l = *(f16x8*)&Ast_l[k0][16 + l15][kh * 32 + l4 * 8];
#pragma unroll
      for (int ni = 0; ni < 4; ++ni) {
        f16x8 bh = *(f16x8*)&Bh[w][ni * 16 + l15][kh * 32 + l4 * 8];
        f16x8 bl = *(f16x8*)&Bl[w][ni * 16 + l15][kh * 32 + l4 * 8];
        acc[0][ni] = __builtin_amdgcn_mfma_f32_16x16x32_f16(a0h, bh, acc[0][ni], 0, 0, 0);
        acc[0][ni] = __builtin_amdgcn_mfma_f32_16x16x32_f16(a0h, bl, acc[0][ni], 0, 0, 0);
        acc[0][ni] = __builtin_amdgcn_mfma_f32_16x16x32_f16(a0l, bh, acc[0][ni], 0, 0, 0);
        acc[1][ni] = __builtin_amdgcn_mfma_f32_16x16x32_f16(a1h, bh, acc[1][ni], 0, 0, 0);
        acc[1][ni] = __builtin_amdgcn_mfma_f32_16x16x32_f16(a1h, bl, acc[1][ni], 0, 0, 0);
        acc[1][ni] = __builtin_amdgcn_mfma_f32_16x16x32_f16(a1l, bh, acc[1][ni], 0, 0, 0);
      }
    }
  }
#pragma unroll
  for (int mi = 0; mi < 2; ++mi)
#pragma unroll
    for (int ni = 0; ni < 4; ++ni) {
      int col = w * 64 + ni * 16 + l15;
      float bv = J.b2[col];
#pragma unroll
      for (int r = 0; r < 4; ++r) {
        int row = bm + mi * 16 + l4 * 4 + r;
        float v = fmaxf(acc[mi][ni][r] + bv, 0.f);
        _Float16 hh, ll;
        splitf(v, hh, ll);
        J.Oh[(size_t)row * 256 + col] = hh;
        J.Ol[(size_t)row * 256 + col] = ll;
      }
    }
}

// ---------------------------------------------------------------------------
// Unified split-f16 MFMA GEMM for QKV, K=256, job table indexed by blockIdx.z.
struct GJob {
  const _Float16* Ah; const _Float16* Al;
  const _Float16* Bh; const _Float16* Bl;
  const float* bias;
  _Float16* Ch; _Float16* Cl; _Float16* Vt;
  float oscale; int flags;
};
struct GJobs { GJob j[6]; };

__global__ __launch_bounds__(256) void k_gemm(GJobs js) {
  const GJob J = js.j[blockIdx.z];
  const int relu = J.flags & 1;
  const int outmode = J.flags >> 4;
  __shared__ _Float16 Ah[64][72], Al[64][72], Bh[64][72], Bl[64][72];
  const int t = threadIdx.x;
  const int bm = blockIdx.x * 64, bn = blockIdx.y * 64;
  const int lane = t & 63, w = t >> 6;
  const int l15 = lane & 15, l4 = lane >> 4;
  const int wm = (w >> 1) * 32, wn = (w & 1) * 32;
  f32x4 acc[2][2] = {};
  for (int k0 = 0; k0 < 256; k0 += 64) {
    __syncthreads();
#pragma unroll
    for (int rep = 0; rep < 2; ++rep) {
      int idx = t + rep * 256;
      int r = idx >> 3, k8 = (idx & 7) * 8;
      size_t offa = (size_t)(bm + r) * 256 + k0 + k8;
      *(f16x8*)&Ah[r][k8] = *(const f16x8*)&J.Ah[offa];
      *(f16x8*)&Al[r][k8] = *(const f16x8*)&J.Al[offa];
      size_t offb = (size_t)(bn + r) * 256 + k0 + k8;
      *(f16x8*)&Bh[r][k8] = *(const f16x8*)&J.Bh[offb];
      *(f16x8*)&Bl[r][k8] = *(const f16x8*)&J.Bl[offb];
    }
    __syncthreads();
#pragma unroll
    for (int kh = 0; kh < 2; ++kh) {
      f16x8 a0h = *(f16x8*)&Ah[wm + l15][kh * 32 + l4 * 8];
      f16x8 a0l = *(f16x8*)&Al[wm + l15][kh * 32 + l4 * 8];
      f16x8 a1h = *(f16x8*)&Ah[wm + 16 + l15][kh * 32 + l4 * 8];
      f16x8 a1l = *(f16x8*)&Al[wm + 16 + l15][kh * 32 + l4 * 8];
      f16x8 b0h = *(f16x8*)&Bh[wn + l15][kh * 32 + l4 * 8];
      f16x8 b0l = *(f16x8*)&Bl[wn + l15][kh * 32 + l4 * 8];
      f16x8 b1h = *(f16x8*)&Bh[wn + 16 + l15][kh * 32 + l4 * 8];
      f16x8 b1l = *(f16x8*)&Bl[wn + 16 + l15][kh * 32 + l4 * 8];
      acc[0][0] = __builtin_amdgcn_mfma_f32_16x16x32_f16(a0h, b0h, acc[0][0], 0, 0, 0);
      acc[0][0] = __builtin_amdgcn_mfma_f32_16x16x32_f16(a0h, b0l, acc[0][0], 0, 0, 0);
      acc[0][0] = __builtin_amdgcn_mfma_f32_16x16x32_f16(a0l, b0h, acc[0][0], 0, 0, 0);
      acc[0][1] = __builtin_amdgcn_mfma_f32_16x16x32_f16(a0h, b1h, acc[0][1], 0, 0, 0);
      acc[0][1] = __builtin_amdgcn_mfma_f32_16x16x32_f16(a0h, b1l, acc[0][1], 0, 0, 0);
      acc[0][1] = __builtin_amdgcn_mfma_f32_16x16x32_f16(a0l, b1h, acc[0][1], 0, 0, 0);
      acc[1][0] = __builtin_amdgcn_mfma_f32_16x16x32_f16(a1h, b0h, acc[1][0], 0, 0, 0);
      acc[1][0] = __builtin_amdgcn_mfma_f32_16x16x32_f16(a1h, b0l, acc[1][0], 0, 0, 0);
      acc[1][0] = __builtin_amdgcn_mfma_f32_16x16x32_f16(a1l, b0h, acc[1][0], 0, 0, 0);
      acc[1][1] = __builtin_amdgcn_mfma_f32_16x16x32_f16(a1h, b1h, acc[1][1], 0, 0, 0);
      acc[1][1] = __builtin_amdgcn_mfma_f32_16x16x32_f16(a1h, b1l, acc[1][1], 0, 0, 0);
      acc[1][1] = __builtin_amdgcn_mfma_f32_16x16x32_f16(a1l, b1h, acc[1][1], 0, 0, 0);
    }
  }
  if (outmode == 3) __syncthreads();
#pragma unroll
  for (int mi = 0; mi < 2; ++mi)
#pragma unroll
    for (int ni = 0; ni < 2; ++ni) {
      int col = bn + wn + ni * 16 + l15;
      float bv = J.bias[col];
#pragma unroll
      for (int r = 0; r < 4; ++r) {
        int row = bm + wm + mi * 16 + l4 * 4 + r;
        float v = acc[mi][ni][r] + bv;
        if (relu) v = fmaxf(v, 0.f);
        if (outmode == 1) {
          float vs = v * J.oscale;
          _Float16 hh, ll;
          splitf(vs, hh, ll);
          J.Ch[(size_t)row * 256 + col] = hh;
          J.Cl[(size_t)row * 256 + col] = ll;
        } else {
          Ah[wn + ni * 16 + l15][wm + mi * 16 + l4 * 4 + r] = (_Float16)v;
        }
      }
    }
  if (outmode == 3) {
    __syncthreads();
#pragma unroll
    for (int rep = 0; rep < 2; ++rep) {
      int idx = t + rep * 256;
      int d = idx >> 3, n8 = (idx & 7) * 8;
      *(f16x8*)&J.Vt[(size_t)(bn + d) * 4096 + bm + n8] = *(f16x8*)&Ah[d][n8];
    }
  }
}

// ---------------------------------------------------------------------------
// Swapped-QK flash attention, 128 q/block, quarter k-split. Grid 32x8x4.
struct AttnArgs {
  const _Float16* Qh[2]; const _Float16* Ql[2];
  const _Float16* Kh[2]; const _Float16* Kl[2];
  const _Float16* Vth[2];
  _Float16* Opart; float* mpart; float* lpart;
};

__global__ __launch_bounds__(256) void k_attn6(AttnArgs A, int nkq) {
  __shared__ _Float16 Ksh[64][72], Ksl[64][72];
  __shared__ _Float16 Vsh[64][72];
  __shared__ _Float16 Psh[4][32][72];
  const int t = threadIdx.x;
  const int dir = blockIdx.y >> 2, h = blockIdx.y & 3;
  const int q0 = blockIdx.x * 128;
  const int quarter = blockIdx.z;
  const int kbase = quarter * nkq;
  const int lane = t & 63, w = t >> 6;
  const int l15 = lane & 15, l4 = lane >> 4;
  const int qw = q0 + w * 32;

  const _Float16* Qh_g = A.Qh[dir];
  const _Float16* Ql_g = A.Ql[dir];
  const _Float16* Kh_g = A.Kh[dir];
  const _Float16* Kl_g = A.Kl[dir];
  const _Float16* Vth_g = A.Vth[dir];

  f16x8 qh[2][2], ql[2][2];
#pragma unroll
  for (int qf = 0; qf < 2; ++qf) {
    size_t qoff = (size_t)(qw + qf * 16 + l15) * 256 + h * 64;
#pragma unroll
    for (int kh = 0; kh < 2; ++kh) {
      qh[qf][kh] = *(const f16x8*)&Qh_g[qoff + kh * 32 + l4 * 8];
      ql[qf][kh] = *(const f16x8*)&Ql_g[qoff + kh * 32 + l4 * 8];
    }
  }
  f32x4 o[2][4] = {};
  float mrun[2] = {-1e30f, -1e30f};
  float lrun[2] = {0.f, 0.f};

  for (int kt = 0; kt < nkq; kt += 64) {
    const int k0 = kbase + kt;
    __syncthreads();
#pragma unroll
    for (int rep = 0; rep < 2; ++rep) {
      int idx = t + rep * 256;
      int r = idx >> 3, c8 = idx & 7;
      size_t koff = (size_t)(k0 + r) * 256 + h * 64 + c8 * 8;
      *(f16x8*)&Ksh[r][c8 * 8] = *(const f16x8*)&Kh_g[koff];
      *(f16x8*)&Ksl[r][c8 * 8] = *(const f16x8*)&Kl_g[koff];
      int sc = c8 ^ ((r >> 3) & 7);
      size_t voff = (size_t)(h * 64 + r) * 4096 + k0 + c8 * 8;
      *(f16x8*)&Vsh[r][sc * 8] = *(const f16x8*)&Vth_g[voff];
    }
    __syncthreads();

    f32x4 sf[2][4] = {};
#pragma unroll
    for (int kc = 0; kc < 4; ++kc) {
      f16x8 kf0h = *(f16x8*)&Ksh[kc * 16 + l15][l4 * 8];
      f16x8 kf0l = *(f16x8*)&Ksl[kc * 16 + l15][l4 * 8];
      f16x8 kf1h = *(f16x8*)&Ksh[kc * 16 + l15][32 + l4 * 8];
      f16x8 kf1l = *(f16x8*)&Ksl[kc * 16 + l15][32 + l4 * 8];
#pragma unroll
      for (int qf = 0; qf < 2; ++qf) {
        sf[qf][kc] = __builtin_amdgcn_mfma_f32_16x16x32_f16(kf0h, qh[qf][0], sf[qf][kc], 0, 0, 0);
        sf[qf][kc] = __builtin_amdgcn_mfma_f32_16x16x32_f16(kf0h, ql[qf][0], sf[qf][kc], 0, 0, 0);
        sf[qf][kc] = __builtin_amdgcn_mfma_f32_16x16x32_f16(kf0l, qh[qf][0], sf[qf][kc], 0, 0, 0);
        sf[qf][kc] = __builtin_amdgcn_mfma_f32_16x16x32_f16(kf1h, qh[qf][1], sf[qf][kc], 0, 0, 0);
        sf[qf][kc] = __builtin_amdgcn_mfma_f32_16x16x32_f16(kf1h, ql[qf][1], sf[qf][kc], 0, 0, 0);
        sf[qf][kc] = __builtin_amdgcn_mfma_f32_16x16x32_f16(kf1l, qh[qf][1], sf[qf][kc], 0, 0, 0);
      }
    }

#pragma unroll
    for (int qf = 0; qf < 2; ++qf) {
      float mt = -1e30f;
#pragma unroll
      for (int kc = 0; kc < 4; ++kc) {
        float a = fmaxf(fmaxf(sf[qf][kc][0], sf[qf][kc][1]),
                        fmaxf(sf[qf][kc][2], sf[qf][kc][3]));
        mt = fmaxf(mt, a);
      }
      mt = fmaxf(mt, __shfl_xor(mt, 16, 64));
      mt = fmaxf(mt, __shfl_xor(mt, 32, 64));
      float mn = fmaxf(mrun[qf], mt);
      float alpha = __expf(mrun[qf] - mn);
      mrun[qf] = mn;
      float rs = 0.f;
#pragma unroll
      for (int kc = 0; kc < 4; ++kc) {
        float p0 = __expf(sf[qf][kc][0] - mn);
        float p1 = __expf(sf[qf][kc][1] - mn);
        float p2 = __expf(sf[qf][kc][2] - mn);
        float p3 = __expf(sf[qf][kc][3] - mn);
        rs += (p0 + p1) + (p2 + p3);
        f16x4 pv = {(_Float16)p0, (_Float16)p1, (_Float16)p2, (_Float16)p3};
        *(f16x4*)&Psh[w][qf * 16 + l15][kc * 16 + 4 * l4] = pv;
      }
      rs += __shfl_xor(rs, 16, 64);
      rs += __shfl_xor(rs, 32, 64);
      lrun[qf] = lrun[qf] * alpha + rs;
#pragma unroll
      for (int r = 0; r < 4; ++r) {
        float ar = __shfl(alpha, 4 * l4 + r, 64);
        o[qf][0][r] *= ar; o[qf][1][r] *= ar;
        o[qf][2][r] *= ar; o[qf][3][r] *= ar;
      }
    }

#pragma unroll
    for (int kh = 0; kh < 2; ++kh) {
      f16x8 pa0 = *(f16x8*)&Psh[w][l15][kh * 32 + l4 * 8];
      f16x8 pa1 = *(f16x8*)&Psh[w][16 + l15][kh * 32 + l4 * 8];
#pragma unroll
      for (int oc = 0; oc < 4; ++oc) {
        int d = oc * 16 + l15;
        int chunk = (kh * 4 + l4) ^ ((d >> 3) & 7);
        f16x8 vb = *(f16x8*)&Vsh[d][chunk * 8];
        o[0][oc] = __builtin_amdgcn_mfma_f32_16x16x32_f16(pa0, vb, o[0][oc], 0, 0, 0);
        o[1][oc] = __builtin_amdgcn_mfma_f32_16x16x32_f16(pa1, vb, o[1][oc], 0, 0, 0);
      }
    }
  }

  const int slot = dir * 4 + quarter;
#pragma unroll
  for (int qf = 0; qf < 2; ++qf)
#pragma unroll
    for (int oc = 0; oc < 4; ++oc) {
      int col = h * 64 + oc * 16 + l15;
#pragma unroll
      for (int r = 0; r < 4; ++r) {
        int row = qw + qf * 16 + 4 * l4 + r;
        A.Opart[((size_t)slot * 4096 + row) * 256 + col] = (_Float16)o[qf][oc][r];
      }
    }
  if (lane < 16) {
#pragma unroll
    for (int qf = 0; qf < 2; ++qf) {
      int row = qw + qf * 16 + l15;
      A.mpart[(size_t)(slot * 4 + h) * 4096 + row] = mrun[qf];
      A.lpart[(size_t)(slot * 4 + h) * 4096 + row] = lrun[qf];
    }
  }
}

// ---------------------------------------------------------------------------
// Combine 4 k-quarters + residual + segment-sum pooling. Grid (4096, 2).
__global__ __launch_bounds__(256) void k_combine_pool(
    const _Float16* __restrict__ Opart, const float* __restrict__ mpart,
    const float* __restrict__ lpart,
    const _Float16* __restrict__ hmh, const _Float16* __restrict__ hml,
    const _Float16* __restrict__ hph, const _Float16* __restrict__ hpl,
    const int* __restrict__ b_mol, const int* __restrict__ b_prot,
    float* __restrict__ z, float* __restrict__ cnt) {
  const int row = blockIdx.x;
  const int dir = blockIdx.y;
  const int c = threadIdx.x;
  const int h = c >> 6;
  const _Float16* Hh = dir ? hph : hmh;
  const _Float16* Hl = dir ? hpl : hml;
  const int g = (dir ? b_prot : b_mol)[row];
  float mv[4], lv[4], M = -1e30f;
#pragma unroll
  for (int q = 0; q < 4; ++q) {
    int slot = dir * 4 + q;
    mv[q] = mpart[(size_t)(slot * 4 + h) * 4096 + row];
    lv[q] = lpart[(size_t)(slot * 4 + h) * 4096 + row];
    M = fmaxf(M, mv[q]);
  }
  float L = 0.f, acc = 0.f;
#pragma unroll
  for (int q = 0; q < 4; ++q) {
    float e = __expf(mv[q] - M);
    L += lv[q] * e;
    acc += (float)Opart[((size_t)(dir * 4 + q) * 4096 + row) * 256 + c] * e;
  }
  float hin = (float)Hh[(size_t)row * 256 + c] + (float)Hl[(size_t)row * 256 + c];
  float v = acc / L + hin;
  atomicAdd(&z[(size_t)g * 512 + dir * 256 + c], v);
  if (c == 0) atomicAdd(&cnt[dir * 32 + g], 1.0f);
}

// ---------------------------------------------------------------------------
// Fused head: z-mean -> fc1+relu -> fc2 -> sigmoid. 32 blocks.
__global__ __launch_bounds__(256) void k_head(
    const float* __restrict__ z, const float* __restrict__ cnt,
    const float* __restrict__ w1, const float* __restrict__ b1,
    const float* __restrict__ w2, const float* __restrict__ b2,
    float* __restrict__ out) {
  __shared__ float wsum[4];
  const int r = blockIdx.x;
  const int c = threadIdx.x;
  const float im = 1.0f / fmaxf(cnt[r], 1.0f);
  const float ip = 1.0f / fmaxf(cnt[32 + r], 1.0f);
  float acc = b1[c];
  for (int k = 0; k < 256; ++k) acc += (z[r * 512 + k] * im) * w1[k * HDIM + c];
  for (int k = 256; k < 512; ++k) acc += (z[r * 512 + k] * ip) * w1[k * HDIM + c];
  acc = fmaxf(acc, 0.f);
  float p = acc * w2[c];
#pragma unroll
  for (int off = 1; off < 64; off <<= 1) p += __shfl_xor(p, off, 64);
  if ((c & 63) == 0) wsum[c >> 6] = p;
  __syncthreads();
  if (c == 0) {
    float s = (wsum[0] + wsum[1]) + (wsum[2] + wsum[3]) + b2[0];
    out[r] = 1.0f / (1.0f + __expf(-s));
  }
}

// ---------------------------------------------------------------------------
extern "C" void kernel_launch(void* const* d_in, const int* in_sizes, int n_in,
                              void* d_out, int out_size, void* d_ws, size_t ws_size,
                              hipStream_t stream) {
  const float* x_mol   = (const float*)d_in[0];
  const float* x_prot  = (const float*)d_in[1];
  const float* ea_mol  = (const float*)d_in[2];
  const float* ea_prot = (const float*)d_in[3];
  const int*   ei_mol  = (const int*)d_in[4];
  const int*   ei_prot = (const int*)d_in[5];
  const int*   b_mol   = (const int*)d_in[6];
  const int*   b_prot  = (const int*)d_in[7];
  const float* nlm_w = (const float*)d_in[8];
  const float* nlm_b = (const float*)d_in[9];
  const float* nlp_w = (const float*)d_in[10];
  const float* nlp_b = (const float*)d_in[11];
  const float* elm_w = (const float*)d_in[12];
  const float* elm_b = (const float*)d_in[13];
  const float* elp_w = (const float*)d_in[14];
  const float* elp_b = (const float*)d_in[15];
  const float* mol_w1 = (const float*)d_in[16];
  const float* mol_b1 = (const float*)d_in[17];
  const float* mol_w2 = (const float*)d_in[18];
  const float* mol_b2 = (const float*)d_in[19];
  const float* prot_w1 = (const float*)d_in[20];
  const float* prot_b1 = (const float*)d_in[21];
  const float* prot_w2 = (const float*)d_in[22];
  const float* prot_b2 = (const float*)d_in[23];
  const float* mp_wq = (const float*)d_in[24];
  const float* mp_bq = (const float*)d_in[25];
  const float* mp_wk = (const float*)d_in[26];
  const float* mp_bk = (const float*)d_in[27];
  const float* mp_wv = (const float*)d_in[28];
  const float* mp_bv = (const float*)d_in[29];
  const float* pm_wq = (const float*)d_in[30];
  const float* pm_bq = (const float*)d_in[31];
  const float* pm_wk = (const float*)d_in[32];
  const float* pm_bk = (const float*)d_in[33];
  const float* pm_wv = (const float*)d_in[34];
  const float* pm_bv = (const float*)d_in[35];
  const float* fc1_w = (const float*)d_in[36];
  const float* fc1_b = (const float*)d_in[37];
  const float* fc2_w = (const float*)d_in[38];
  const float* fc2_b = (const float*)d_in[39];
  float* out = (float*)d_out;

  // workspace carve (MB offsets); peak ~61 MB
  char* W8 = (char*)d_ws;
  const size_t MB = 1u << 20;
  _Float16* wtH  = (_Float16*)(W8 + 0 * MB);
  _Float16* wtL  = (_Float16*)(W8 + 2 * MB);
  _Float16* hmh  = (_Float16*)(W8 + 4 * MB);
  _Float16* hml  = (_Float16*)(W8 + 6 * MB);
  _Float16* hph  = (_Float16*)(W8 + 8 * MB);
  _Float16* hpl  = (_Float16*)(W8 + 10 * MB);
  _Float16* amh  = (_Float16*)(W8 + 12 * MB);
  _Float16* aml  = (_Float16*)(W8 + 14 * MB);
  _Float16* aph  = (_Float16*)(W8 + 16 * MB);
  _Float16* apl  = (_Float16*)(W8 + 18 * MB);
  _Float16* Qh0  = (_Float16*)(W8 + 20 * MB);
  _Float16* Ql0  = (_Float16*)(W8 + 22 * MB);
  _Float16* Kh0  = (_Float16*)(W8 + 24 * MB);
  _Float16* Kl0  = (_Float16*)(W8 + 26 * MB);
  _Float16* Qh1  = (_Float16*)(W8 + 28 * MB);
  _Float16* Ql1  = (_Float16*)(W8 + 30 * MB);
  _Float16* Kh1  = (_Float16*)(W8 + 32 * MB);
  _Float16* Kl1  = (_Float16*)(W8 + 34 * MB);
  _Float16* Vth0 = (_Float16*)(W8 + 36 * MB);
  _Float16* Vth1 = (_Float16*)(W8 + 38 * MB);
  _Float16* Opart = (_Float16*)(W8 + 40 * MB);  // 16 MB: [8 slots][4096][256] f16
  float* mpart = (float*)(W8 + 56 * MB);        // 32*4096 floats (512 KB)
  float* lpart = (float*)(W8 + 56 * MB + 512 * 1024);
  int* off_m = (int*)(W8 + 57 * MB);
  int* off_p = off_m + 8192;
  float* zb  = (float*)(off_p + 8192);          // 32*512
  float* cnt = zb + 32 * 512;                   // 64
  EdgeRec* er_m = (EdgeRec*)(W8 + 58 * MB);     // 1 MB
  EdgeRec* er_p = (EdgeRec*)(W8 + 59 * MB);     // 1 MB

  // weights: 0,1 mol_w1 | 2,3 mol_w2 | 4,5 prot_w1 | 6,7 prot_w2
  // 8 mp_wq 9 mp_wk 10 mp_wv | 11 pm_wq 12 pm_wk 13 pm_wv
  PtrPack pk;
  pk.p[0] = mol_w1;           pk.p[1] = mol_w1 + 65536;
  pk.p[2] = mol_w2;           pk.p[3] = mol_w2 + 65536;
  pk.p[4] = prot_w1;          pk.p[5] = prot_w1 + 65536;
  pk.p[6] = prot_w2;          pk.p[7] = prot_w2 + 65536;
  pk.p[8] = mp_wq;  pk.p[9] = mp_wk;  pk.p[10] = mp_wv;
  pk.p[11] = pm_wq; pk.p[12] = pm_wk; pk.p[13] = pm_wv;
  k_prep_wt<<<dim3(4, 4, 14), 256, 0, stream>>>(pk, wtH, wtL);

  k_csr_all<<<2, 1024, 0, stream>>>(ei_mol, ei_prot, ea_mol, ea_prot,
                                    off_m, off_p, er_m, er_p);

  EmbJob em = {x_mol, nlm_w, nlm_b, hmh, hml, 8};
  EmbJob ep = {x_prot, nlp_w, nlp_b, hph, hpl, 4};
  k_node_embed2<<<dim3(NMOL, 2), 256, 0, stream>>>(em, ep);

#define WTH(i) (wtH + (size_t)(i) * 65536)
#define WTL(i) (wtL + (size_t)(i) * 65536)

  AggJob am = {hmh, hml, er_m, off_m, elm_w, elm_b, amh, aml};
  AggJob ap = {hph, hpl, er_p, off_p, elp_w, elp_b, aph, apl};

  for (int l = 0; l < 2; ++l) {
    k_agg2<<<dim3(NMOL, 2), 256, 0, stream>>>(am, ap);
    FusedJob fm = {amh, aml, WTH(l), WTL(l), mol_b1 + l * 256,
                   WTH(2 + l), WTL(2 + l), mol_b2 + l * 256, hmh, hml};
    FusedJob fp = {aph, apl, WTH(4 + l), WTL(4 + l), prot_b1 + l * 256,
                   WTH(6 + l), WTL(6 + l), prot_b2 + l * 256, hph, hpl};
    k_gine_fused<<<dim3(128, 2), 256, 0, stream>>>(fm, fp);
  }

  // QKV for both attention directions, one dispatch (z=6); V transposed in-epilogue
  {
    GJobs q = {};
    q.j[0] = {hmh, hml, WTH(8), WTL(8), mp_bq, Qh0, Ql0, nullptr, 0.125f, 1 << 4};
    q.j[1] = {hph, hpl, WTH(9), WTL(9), mp_bk, Kh0, Kl0, nullptr, 1.0f, 1 << 4};
    q.j[2] = {hph, hpl, WTH(10), WTL(10), mp_bv, nullptr, nullptr, Vth0, 1.0f, 3 << 4};
    q.j[3] = {hph, hpl, WTH(11), WTL(11), pm_bq, Qh1, Ql1, nullptr, 0.125f, 1 << 4};
    q.j[4] = {hmh, hml, WTH(12), WTL(12), pm_bk, Kh1, Kl1, nullptr, 1.0f, 1 << 4};
    q.j[5] = {hmh, hml, WTH(13), WTL(13), pm_bv, nullptr, nullptr, Vth1, 1.0f, 3 << 4};
    k_gemm<<<dim3(64, 4, 6), 256, 0, stream>>>(q);
  }

  AttnArgs aa;
  aa.Qh[0] = Qh0; aa.Ql[0] = Ql0; aa.Kh[0] = Kh0; aa.Kl[0] = Kl0; aa.Vth[0] = Vth0;
  aa.Qh[1] = Qh1; aa.Ql[1] = Ql1; aa.Kh[1] = Kh1; aa.Kl[1] = Kl1; aa.Vth[1] = Vth1;
  aa.Opart = Opart; aa.mpart = mpart; aa.lpart = lpart;
  k_attn6<<<dim3(32, 8, 4), 256, 0, stream>>>(aa, 1024);

  hipMemsetAsync(zb, 0, (32 * 512 + 64) * 4, stream);
  k_combine_pool<<<dim3(4096, 2), 256, 0, stream>>>(Opart, mpart, lpart,
                                                    hmh, hml, hph, hpl,
                                                    b_mol, b_prot, zb, cnt);
  k_head<<<NG, 256, 0, stream>>>(zb, cnt, fc1_w, fc1_b, fc2_w, fc2_b, out);
#undef WTH
#undef WTL
}